// Round 5
// baseline (19513.808 us; speedup 1.0000x reference)
//
#include <hip/hip_runtime.h>
#include <math.h>

#define NBLK 128
#define NTHR 512
#define Bz 128
#define Sz 1024
#define Hz 512
#define BUFU 131072          // u32 per HS buffer: 128 rows x 1024 cols
#define WKS  4096            // LDS bytes per ks: 2 tiles x (hi+lo) x 1024B
#define ZOFF 131072          // LDS byte offset of z-exchange area
#define DPF  8               // prefetch depth in 32-k steps

typedef float        f32x4 __attribute__((ext_vector_type(4)));
typedef short        s16x8 __attribute__((ext_vector_type(8)));
typedef unsigned int u32x4 __attribute__((ext_vector_type(4)));

__device__ __forceinline__ float sigm_(float x){ return 1.0f/(1.0f + __expf(-x)); }
__device__ __forceinline__ float tanh_(float x){
  float e = __expf(-2.0f*fabsf(x));
  float t2 = (1.0f - e)/(1.0f + e);
  return copysignf(t2, x);
}
__device__ __forceinline__ unsigned f2bf(float x){
  unsigned u = __float_as_uint(x);
  return (u + 0x7fffu + ((u>>16)&1u)) >> 16;
}
__device__ __forceinline__ float bf2f(unsigned h){ return __uint_as_float(h<<16); }
__device__ __forceinline__ unsigned packh(float x){   // hi | lo<<16, x ~= hi+lo to 2^-17
  unsigned hi = f2bf(x);
  unsigned lo = f2bf(x - bf2f(hi));
  return hi | (lo<<16);
}

// ---- proven coherence primitives (R2/R3) ----
__device__ __forceinline__ void st_flag(int* p, int v){
  asm volatile("global_store_dword %0, %1, off sc0 sc1\n\ts_waitcnt vmcnt(0)"
               :: "v"(p), "v"(v) : "memory");
}
__device__ __forceinline__ void sth_u(unsigned* p, unsigned v){
  __hip_atomic_store(p, v, __ATOMIC_RELAXED, __HIP_MEMORY_SCOPE_AGENT);
}
__device__ __forceinline__ unsigned ldh_u(const unsigned* p){
  return __hip_atomic_load(p, __ATOMIC_RELAXED, __HIP_MEMORY_SCOPE_AGENT);
}

// R5 FIX: waitcnt that *produces* the staged registers as tied "+v" operands.
// R4's bare volatile wait let the compiler schedule the register-only repack/
// MFMA consumers BEFORE the wait (no dataflow edge) -> stale register reads.
__device__ __forceinline__ void wait_dep14(u32x4& a, u32x4& b){
  asm volatile("s_waitcnt vmcnt(14)" : "+v"(a), "+v"(b) :: "memory");
}
__device__ __forceinline__ void wait_dep0(u32x4& a, u32x4& b){
  asm volatile("s_waitcnt vmcnt(0)" : "+v"(a), "+v"(b) :: "memory");
}
#define WAIT_LGKM() asm volatile("s_waitcnt lgkmcnt(0)" ::: "memory")

extern "C" __global__ void __launch_bounds__(NTHR, 2)
qlstm_kern(const int* __restrict__ x, const float* __restrict__ emb,
           const float* __restrict__ W0, const float* __restrict__ b0v, const float* __restrict__ bb0v,
           const float* __restrict__ W1, const float* __restrict__ b1v, const float* __restrict__ bb1v,
           const float* __restrict__ fcw, const float* __restrict__ fcb,
           float* __restrict__ out, float* __restrict__ ws)
{
  extern __shared__ char sm[];
  const int t   = threadIdx.x;
  const int bid = blockIdx.x;
  const bool isL0 = (bid < 64);
  const int gbase = (isL0 ? bid : bid - 64) << 3;   // 8 hidden cols per block
  const int K  = isL0 ? 768 : 1024;
  const int KS = K >> 5;                            // 24 / 32 k-steps
  const int koff = isL0 ? 256 : 0;                  // A index offset into HS cols

  const int lane = t & 63;
  const int mt   = t >> 6;            // wave id = M-tile (16 batch rows)
  const int m16  = lane & 15;
  const int q4   = lane >> 4;
  const int b_g  = mt*16 + m16;       // this lane's A row (batch)

  unsigned* HS = (unsigned*)ws;                 // [2][128][1024] packed bf16-pair
  int* flags = (int*)(HS + 2*BUFU);

  // zero h state through the coherent path
  for (int i = bid*NTHR + t; i < 2*BUFU; i += NBLK*NTHR) sth_u(&HS[i], 0u);

  // ---- one-time W -> LDS B-frag layout: [ks][tile][hi|lo][lane*16B] ----
  {
    const float* Wsrc = isL0 ? W0 : W1;
    const int gtot = KS * 128;
    for (int idx = t; idx < gtot; idx += NTHR){
      const int ks = idx >> 7, r = idx & 127;
      const int tile = r >> 6, ln = r & 63;
      const int q = ln >> 4, n = ln & 15;
      const int zrow = (n & 3)*Hz + gbase + tile*4 + (n >> 2);  // gate=n&3, hid=n>>2
      const float* src = Wsrc + (size_t)zrow*K + ks*32 + q*8;
      const float4 e0 = *(const float4*)(src);
      const float4 e1 = *(const float4*)(src + 4);
      float ev[8] = {e0.x,e0.y,e0.z,e0.w,e1.x,e1.y,e1.z,e1.w};
      unsigned hiw[4], low[4];
      #pragma unroll
      for (int k2 = 0; k2 < 4; ++k2){
        unsigned ha = f2bf(ev[2*k2]),   hb = f2bf(ev[2*k2+1]);
        unsigned la = f2bf(ev[2*k2]   - bf2f(ha));
        unsigned lb = f2bf(ev[2*k2+1] - bf2f(hb));
        hiw[k2] = ha | (hb << 16);
        low[k2] = la | (lb << 16);
      }
      char* dst = sm + ks*WKS + tile*2048 + ln*16;
      *(u32x4*)(dst)        = (u32x4){hiw[0],hiw[1],hiw[2],hiw[3]};
      *(u32x4*)(dst + 1024) = (u32x4){low[0],low[1],low[2],low[3]};
    }
  }

  // epilogue identity: lane owns (hid = lane>>4, bb = lane&15) per tile
  const int e_hid = lane >> 4, e_b = lane & 15;
  const float* bsrc  = isL0 ? b0v  : b1v;
  const float* bbsrc = isL0 ? bb0v : bb1v;
  float bias[2][4];
  #pragma unroll
  for (int tile = 0; tile < 2; ++tile)
    #pragma unroll
    for (int g = 0; g < 4; ++g){
      const int gc = gbase + tile*4 + e_hid;
      bias[tile][g] = bsrc[g*Hz + gc] + bbsrc[g*Hz + gc];
    }

  float creg[2] = {0.f, 0.f};
  float* zp = (float*)sm;
  const int zb = (ZOFF >> 2) + mt*2*272;   // per-wave z zones (272 dw per tile)

  auto gridbar = [&](int epoch){
    __syncthreads();                          // drains each wave's vmcnt -> h at L3
    if (t == 0) st_flag(&flags[bid], epoch);
    if (t < 32){
      int mn;
      do {
        u32x4 f;
        asm volatile("global_load_dwordx4 %0, %1, off sc0 sc1\n\ts_waitcnt vmcnt(0)"
                     : "=v"(f) : "v"(flags + 4*t) : "memory");
        int a0 = (int)f.x < (int)f.y ? (int)f.x : (int)f.y;
        int a1 = (int)f.z < (int)f.w ? (int)f.z : (int)f.w;
        mn = a0 < a1 ? a0 : a1;
        if (mn < epoch) __builtin_amdgcn_s_sleep(1);
      } while (__ballot(mn < epoch));
    }
    __syncthreads();
  };

  int xr = isL0 ? x[b_g*Sz] : 0;   // row for p=0 (prefetched each epilogue after)

  gridbar(1);

  for (int p = 0; p <= Sz; ++p){
    const int rb = (p + 1) & 1;
    const int wb = p & 1;
    const bool active = isL0 ? (p < Sz) : (p >= 1);
    if (active){
      // per-lane base pointers for direct A-fragment loads
      const unsigned* hL  = HS + rb*BUFU + b_g*1024 + q4*8 - koff;
      const float*   embL = emb + (size_t)xr*256 + q4*8;
      asm volatile("s_waitcnt vmcnt(0)" ::: "memory");   // clean counter baseline

      u32x4 st[DPF][2];
      f32x4 acc[2] = {{0.f,0.f,0.f,0.f},{0.f,0.f,0.f,0.f}};

      auto ISS = [&](int ks, u32x4* s){
        if (isL0 && ks < 8){
          const float* pp = embL + ks*32;
          asm volatile("global_load_dwordx4 %0, %2, off\n\tglobal_load_dwordx4 %1, %3, off"
            : "=v"(s[0]), "=v"(s[1]) : "v"(pp), "v"(pp+4) : "memory");
        } else {
          const unsigned* pp = hL + ks*32;
          asm volatile("global_load_dwordx4 %0, %2, off sc0 sc1\n\tglobal_load_dwordx4 %1, %3, off sc0 sc1"
            : "=v"(s[0]), "=v"(s[1]) : "v"(pp), "v"(pp+4) : "memory");
        }
      };

      auto CMP = [&](int ks, const u32x4* s){
        u32x4 ah, al;
        if (isL0 && ks < 8){
          // emb path: f32 -> hi/lo bf16 pairs
          const f32x4 e0 = __builtin_bit_cast(f32x4, s[0]);
          const f32x4 e1 = __builtin_bit_cast(f32x4, s[1]);
          float ev[8] = {e0.x,e0.y,e0.z,e0.w,e1.x,e1.y,e1.z,e1.w};
          #pragma unroll
          for (int k2 = 0; k2 < 4; ++k2){
            unsigned ha = f2bf(ev[2*k2]),   hb = f2bf(ev[2*k2+1]);
            unsigned la = f2bf(ev[2*k2]   - bf2f(ha));
            unsigned lb = f2bf(ev[2*k2+1] - bf2f(hb));
            ah[k2] = ha | (hb << 16);
            al[k2] = la | (lb << 16);
          }
        } else {
          // h path: already packed hi|lo per element; regroup to plane vectors
          unsigned q[8] = {s[0].x,s[0].y,s[0].z,s[0].w,s[1].x,s[1].y,s[1].z,s[1].w};
          #pragma unroll
          for (int k2 = 0; k2 < 4; ++k2){
            ah[k2] = (q[2*k2] & 0xffffu) | (q[2*k2+1] << 16);
            al[k2] = (q[2*k2] >> 16)     | (q[2*k2+1] & 0xffff0000u);
          }
        }
        const s16x8 fah = __builtin_bit_cast(s16x8, ah);
        const s16x8 fal = __builtin_bit_cast(s16x8, al);
        #pragma unroll
        for (int tile = 0; tile < 2; ++tile){
          const char* wbse = sm + ks*WKS + tile*2048 + lane*16;
          const s16x8 fbh = __builtin_bit_cast(s16x8, *(const u32x4*)(wbse));
          const s16x8 fbl = __builtin_bit_cast(s16x8, *(const u32x4*)(wbse + 1024));
          acc[tile] = __builtin_amdgcn_mfma_f32_16x16x32_bf16(fah, fbh, acc[tile], 0, 0, 0);
          acc[tile] = __builtin_amdgcn_mfma_f32_16x16x32_bf16(fah, fbl, acc[tile], 0, 0, 0);
          acc[tile] = __builtin_amdgcn_mfma_f32_16x16x32_bf16(fal, fbh, acc[tile], 0, 0, 0);
        }
      };

      #pragma unroll
      for (int u = 0; u < DPF; ++u) ISS(u, st[u]);
      for (int ks0 = 0; ks0 < KS - DPF; ks0 += DPF){
        #pragma unroll
        for (int u = 0; u < DPF; ++u){
          wait_dep14(st[u][0], st[u][1]);   // dataflow edge: wait -> CMP operands
          CMP(ks0 + u, st[u]);
          ISS(ks0 + u + DPF, st[u]);
        }
      }
      #pragma unroll
      for (int u = 0; u < DPF; ++u){
        wait_dep0(st[u][0], st[u][1]);      // vmcnt(0) idempotent; carries the dep
        CMP(KS - DPF + u, st[u]);
      }

      // ---- per-wave epilogue: z exchange in private LDS, cell, h store ----
      {
        const int n_ = lane & 15, qr = lane >> 4;
        #pragma unroll
        for (int tile = 0; tile < 2; ++tile)
          #pragma unroll
          for (int r = 0; r < 4; ++r)
            zp[zb + tile*272 + n_*17 + qr*4 + r] = acc[tile][r];
        WAIT_LGKM();
        #pragma unroll
        for (int tile = 0; tile < 2; ++tile){
          float z0 = zp[zb + tile*272 + (e_hid*4 + 0)*17 + e_b];
          float z1 = zp[zb + tile*272 + (e_hid*4 + 1)*17 + e_b];
          float z2 = zp[zb + tile*272 + (e_hid*4 + 2)*17 + e_b];
          float z3 = zp[zb + tile*272 + (e_hid*4 + 3)*17 + e_b];
          const float fg = sigm_(z0 + bias[tile][0]);
          const float ig = sigm_(z1 + bias[tile][1]);
          const float cg = tanh_(z2 + bias[tile][2]);
          const float og = sigm_(z3 + bias[tile][3]);
          creg[tile] = fg*creg[tile] + ig*cg;
          const float hval = og * tanh_(creg[tile]);
          const int col = (isL0 ? 0 : 512) + gbase + tile*4 + e_hid;
          sth_u(&HS[wb*BUFU + (mt*16 + e_b)*1024 + col], packh(hval));
        }
      }
      // prefetch next phase's x row (value used after the barrier)
      if (isL0){
        const int pn = (p + 1 < Sz) ? p + 1 : Sz - 1;
        xr = x[b_g*Sz + pn];
      }
    }
    gridbar(p + 2);
  }

  // final FC: out[b][o] = h1 . fc_w[o] + fc_b[o]; final h1 in buf 0 cols 512..1023
  if (bid == 0 && t < 2*Bz){
    const int ob = t >> 1, oo = t & 1;
    const unsigned* hf = HS + ob*1024 + 512;
    float a = fcb[oo];
    #pragma unroll 8
    for (int h = 0; h < Hz; ++h){
      const unsigned pv = ldh_u(&hf[h]);
      a += (bf2f(pv & 0xffffu) + bf2f(pv >> 16)) * fcw[oo*Hz + h];
    }
    out[ob*2 + oo] = a;
  }
}

extern "C" void kernel_launch(void* const* d_in, const int* in_sizes, int n_in,
                              void* d_out, int out_size, void* d_ws, size_t ws_size,
                              hipStream_t stream) {
  (void)in_sizes; (void)n_in; (void)out_size; (void)ws_size;
  const int*   x   = (const int*)d_in[0];
  const float* emb = (const float*)d_in[1];
  const float* W0  = (const float*)d_in[2];
  const float* b0  = (const float*)d_in[3];
  const float* bb0 = (const float*)d_in[4];
  const float* W1  = (const float*)d_in[5];
  const float* b1  = (const float*)d_in[6];
  const float* bb1 = (const float*)d_in[7];
  const float* fcw = (const float*)d_in[8];
  const float* fcb = (const float*)d_in[9];
  float* out = (float*)d_out;
  float* ws  = (float*)d_ws;

  const size_t shmem = 148480;  // 128KB W frags + 17.4KB z-exchange
  hipFuncSetAttribute((const void*)qlstm_kern,
                      hipFuncAttributeMaxDynamicSharedMemorySize, (int)shmem);

  void* args[] = { (void*)&x, (void*)&emb, (void*)&W0, (void*)&b0, (void*)&bb0,
                   (void*)&W1, (void*)&b1, (void*)&bb1, (void*)&fcw, (void*)&fcb,
                   (void*)&out, (void*)&ws };
  hipLaunchCooperativeKernel((const void*)qlstm_kern, dim3(NBLK), dim3(NTHR),
                             args, (unsigned)shmem, stream);
}